// Round 3
// baseline (154.203 us; speedup 1.0000x reference)
//
#include <hip/hip_runtime.h>

#define DZ 512
#define DT 66048
#define SV_JITTER 1e-4f
#define BIGD 0x3FFFFFFF

typedef __attribute__((ext_vector_type(8))) short bf8;
typedef __attribute__((ext_vector_type(4))) float f4;

__device__ __forceinline__ short f2bf(float f) {
  unsigned u = __builtin_bit_cast(unsigned, f);
  return (short)((u + 0x7FFFu + ((u >> 16) & 1u)) >> 16);
}

__device__ __forceinline__ bf8 cvt8(float4 a, float4 b) {
  bf8 r = { f2bf(a.x), f2bf(a.y), f2bf(a.z), f2bf(a.w),
            f2bf(b.x), f2bf(b.y), f2bf(b.z), f2bf(b.w) };
  return r;
}

// tril/jitter cvt: element t has k-index kbase+t
__device__ __forceinline__ bf8 cvt8_tril(float4 x, float4 y, int kbase, int diag) {
  float v[8] = {x.x, x.y, x.z, x.w, y.x, y.y, y.z, y.w};
  bf8 r;
  #pragma unroll
  for (int t = 0; t < 8; ++t) {
    int k = kbase + t;
    float val = (k < diag) ? v[t] : ((k == diag) ? v[t] + SV_JITTER : 0.f);
    r[t] = f2bf(val);
  }
  return r;
}

// B-operand source for K-step kk, column group g (16 cols each).
__device__ __forceinline__ void b_src(int kk, bool is_z, int c0, int lcol, int q,
                                      const float* __restrict__ Lz,
                                      const float* __restrict__ Ly,
                                      const float* __restrict__ Lyz, int g,
                                      const float4*& p, int& diag, int& kbase,
                                      bool& act) {
  if (is_z) {
    const int k0 = kk * 32;
    const int i = c0 + 16 * g + lcol;  // output col = row of Lz
    act = (k0 <= c0 + 16 * g + 15);    // wave-uniform-per-g tril skip
    p = (const float4*)(Lz + (size_t)i * DZ + k0 + 8 * q);
    diag = i; kbase = k0 + 8 * q;
  } else if (kk < 16) {
    const int k0 = kk * 32;
    act = true;
    p = (const float4*)(Lyz + (size_t)(c0 - DZ + 16 * g + lcol) * DZ + k0 + 8 * q);
    diag = BIGD; kbase = 0;
  } else {  // block-diag einsum step: B[j][i] = tril(Ly[n]) + jitter*I
    act = true;
    const int n = (c0 - DZ) >> 5;
    const int i = 16 * g + lcol;
    p = (const float4*)(Ly + ((size_t)(n * 32 + i)) * 32 + 8 * q);
    diag = i; kbase = 8 * q;
  }
}

// One wave per block; wave owns 32 output columns (2 B-frags x 8 M-frags).
// No LDS, no barriers: waves fully independent, 1-deep register prefetch.
// acc layout per mfma_f32_16x16x32_bf16: col = lane&15, row = 4*(lane>>4)+reg.
__global__ __launch_bounds__(64, 2)
void sv_kernel(const float* __restrict__ m, const float* __restrict__ Lz,
               const float* __restrict__ Ly, const float* __restrict__ Lyz,
               const float* __restrict__ eps, float* __restrict__ out) {
  const int w = blockIdx.x;
  const int c0 = w * 32;
  const int lane = threadIdx.x;
  const int lcol = lane & 15;
  const int q = lane >> 4;
  const bool is_z = (c0 < DZ);
  // z strips: tril => only k-steps up to own columns. y strips: 16 + 1 diag.
  const int nkt = is_z ? (c0 / 32 + 1) : 17;

  f4 acc[2][8];
  #pragma unroll
  for (int g = 0; g < 2; ++g)
    #pragma unroll
    for (int mi = 0; mi < 8; ++mi) acc[g][mi] = f4{0.f, 0.f, 0.f, 0.f};

  // A-fragment base: sample row (16*mi + lcol), k window 8*q..8*q+7
  const float* abase = eps + (size_t)lcol * DT + 8 * q;
  // diag step's A columns are exactly eps[:, c0..c0+32)
  auto ksrc = [&](int kk) { return (!is_z && kk == 16) ? c0 : kk * 32; };

  float4 ax[8][2];     // raw A, 1 K-step
  float4 bx[2][2];     // raw B
  int bdiag[2], bkb[2];
  bool bact[2];

  auto fetchA = [&](int kk) {
    const int ks = ksrc(kk);
    #pragma unroll
    for (int mi = 0; mi < 8; ++mi) {
      const float4* p = (const float4*)(abase + (size_t)mi * 16 * DT + ks);
      ax[mi][0] = p[0]; ax[mi][1] = p[1];
    }
  };
  auto fetchB = [&](int kk) {
    #pragma unroll
    for (int g = 0; g < 2; ++g) {
      const float4* p;
      b_src(kk, is_z, c0, lcol, q, Lz, Ly, Lyz, g, p, bdiag[g], bkb[g], bact[g]);
      if (bact[g]) { bx[g][0] = p[0]; bx[g][1] = p[1]; }
    }
  };

  fetchA(0);
  fetchB(0);

  for (int kk = 0; kk < nkt; ++kk) {
    // convert current raw regs -> MFMA fragments (frees raw regs for prefetch)
    bf8 af[8];
    #pragma unroll
    for (int mi = 0; mi < 8; ++mi) af[mi] = cvt8(ax[mi][0], ax[mi][1]);
    bf8 bfr[2];
    bool act[2];
    const bool plain = (!is_z && kk < 16);
    #pragma unroll
    for (int g = 0; g < 2; ++g) {
      act[g] = bact[g];
      if (act[g])
        bfr[g] = plain ? cvt8(bx[g][0], bx[g][1])
                       : cvt8_tril(bx[g][0], bx[g][1], bkb[g], bdiag[g]);
    }
    // issue next K-step's loads; they land while MFMAs below execute
    if (kk + 1 < nkt) { fetchA(kk + 1); fetchB(kk + 1); }

    #pragma unroll
    for (int g = 0; g < 2; ++g) {
      if (act[g]) {
        #pragma unroll
        for (int mi = 0; mi < 8; ++mi)
          acc[g][mi] =
              __builtin_amdgcn_mfma_f32_16x16x32_bf16(af[mi], bfr[g], acc[g][mi], 0, 0, 0);
      }
    }
  }

  #pragma unroll
  for (int g = 0; g < 2; ++g) {
    const float mval = m[c0 + 16 * g + lcol];
    #pragma unroll
    for (int mi = 0; mi < 8; ++mi) {
      #pragma unroll
      for (int r = 0; r < 4; ++r) {
        const int s = 16 * mi + 4 * q + r;
        out[(size_t)s * DT + c0 + 16 * g + lcol] = acc[g][mi][r] + mval;
      }
    }
  }
}

extern "C" void kernel_launch(void* const* d_in, const int* in_sizes, int n_in,
                              void* d_out, int out_size, void* d_ws, size_t ws_size,
                              hipStream_t stream) {
  const float* m   = (const float*)d_in[0];
  const float* Lz  = (const float*)d_in[1];
  const float* Ly  = (const float*)d_in[2];
  const float* Lyz = (const float*)d_in[3];
  const float* eps = (const float*)d_in[4];
  float* out = (float*)d_out;
  sv_kernel<<<dim3(DT / 32), dim3(64), 0, stream>>>(m, Lz, Ly, Lyz, eps, out);
}

// Round 4
// 63.293 us; speedup vs baseline: 2.4363x; 2.4363x over previous
//
#include <hip/hip_runtime.h>

#define DZ 512
#define DT 66048
#define NSTRIP 1032
#define SV_JITTER 1e-4f
#define BIGD 0x3FFFFFFF

typedef __attribute__((ext_vector_type(8))) short bf8;
typedef __attribute__((ext_vector_type(4))) float f4;

__device__ __forceinline__ short f2bf(float f) {
  unsigned u = __builtin_bit_cast(unsigned, f);
  return (short)((u + 0x7FFFu + ((u >> 16) & 1u)) >> 16);
}

__device__ __forceinline__ bf8 cvt8(float4 a, float4 b) {
  bf8 r = { f2bf(a.x), f2bf(a.y), f2bf(a.z), f2bf(a.w),
            f2bf(b.x), f2bf(b.y), f2bf(b.z), f2bf(b.w) };
  return r;
}

// tril/jitter cvt: element t has k-index kbase+t; diag==BIGD -> plain copy
__device__ __forceinline__ bf8 cvt8_tril(float4 x, float4 y, int kbase, int diag) {
  float v[8] = {x.x, x.y, x.z, x.w, y.x, y.y, y.z, y.w};
  bf8 r;
  #pragma unroll
  for (int t = 0; t < 8; ++t) {
    int k = kbase + t;
    float val = (k < diag) ? v[t] : ((k == diag) ? v[t] + SV_JITTER : 0.f);
    r[t] = f2bf(val);
  }
  return r;
}

// 256 blocks (1/CU) x 512 threads (8 waves = 2/SIMD). Block stages ALL of
// eps_z into LDS in MFMA-frag layout ONCE, then loops 4-5 column strips of 64
// with ZERO barriers: B 4-deep register prefetch, A 2-deep from LDS.
// Wave wv: sample-half mh=wv&1 (rows 64*mh..+63), col-group cg=wv>>1 (16 cols).
// acc layout per mfma_f32_16x16x32_bf16: col=lane&15, row=4*(lane>>4)+reg.
__global__ __launch_bounds__(512, 2)
void sv_kernel(const float* __restrict__ mv, const float* __restrict__ Lz,
               const float* __restrict__ Ly, const float* __restrict__ Lyz,
               const float* __restrict__ eps, float* __restrict__ out) {
  // frag layout: region r = kk*8+mi (kk=K-step 0..15, mi=sample-row/16),
  // 64 slots x 16B: slot==lane holds eps[16*mi+(lane&15)][kk*32+(lane>>4)*8 ..+7]
  __shared__ short Afrag[128 * 512];  // 128 KB

  const int tid = threadIdx.x;
  const int lane = tid & 63;
  const int wv = tid >> 6;
  const int lcol = lane & 15;
  const int q = lane >> 4;
  const int mh = wv & 1;
  const int cg = wv >> 1;
  const int rbase = 4 * mh;

  // ---- stage eps_z (once): warp-uniform region, slot=lane -> linear ds_write
  {
    const int slot = tid & 63;
    const int r0 = (tid >> 6) * 16;
    #pragma unroll 4
    for (int i = 0; i < 16; ++i) {
      const int r = r0 + i;  // 0..127
      const float* p = eps + (size_t)(16 * (r & 7) + (slot & 15)) * DT +
                       (r >> 3) * 32 + (slot >> 4) * 8;
      float4 x = *(const float4*)p;
      float4 y = *(const float4*)(p + 4);
      *(bf8*)&Afrag[r * 512 + slot * 8] = cvt8(x, y);
    }
  }
  __syncthreads();  // the ONLY barrier

  for (int j = 0; j < 5; ++j) {
    const int s = blockIdx.x + 256 * j;  // strips: b, b+256, b+512, b+768 (+1024+b for b<8)
    if (s >= NSTRIP) break;
    const bool is_z = (s < 8);
    const int c0 = s * 64 + 16 * cg;
    const int colL = c0 + lcol;  // lane's output column
    const int bdiag = is_z ? colL : BIGD;
    const float* bptr = is_z ? (Lz + (size_t)colL * DZ)
                             : (Lyz + (size_t)(colL - DZ) * DZ);

    f4 acc[4];
    #pragma unroll
    for (int mi = 0; mi < 4; ++mi) acc[mi] = f4{0.f, 0.f, 0.f, 0.f};

    float4 bx0, by0, bx1, by1, bx2, by2, bx3, by3;
    bf8 a0[4], a1[4];

    auto loadB = [&](int kk, float4& x, float4& y) {
      const float* p = bptr + kk * 32 + 8 * q;
      x = *(const float4*)p;
      y = *(const float4*)(p + 4);
    };
    auto loadA = [&](int kk, bf8* a) {
      #pragma unroll
      for (int mi = 0; mi < 4; ++mi)
        a[mi] = *(const bf8*)&Afrag[(kk * 8 + rbase + mi) * 512 + lane * 8];
    };
    auto domfma = [&](const bf8* a, bf8 bf) {
      #pragma unroll
      for (int mi = 0; mi < 4; ++mi)
        acc[mi] = __builtin_amdgcn_mfma_f32_16x16x32_bf16(a[mi], bf, acc[mi], 0, 0, 0);
    };

    // prologue: B 4-deep, A 2-deep
    loadB(0, bx0, by0); loadB(1, bx1, by1);
    loadB(2, bx2, by2); loadB(3, bx3, by3);
    loadA(0, a0); loadA(1, a1);

    int kk = 0;
    #pragma unroll 1
    for (int kt = 0; kt < 3; ++kt, kk += 4) {  // steps 0..11; all refills < 16
      { bf8 bf = cvt8_tril(bx0, by0, kk * 32 + 8 * q, bdiag);
        domfma(a0, bf); loadB(kk + 4, bx0, by0); loadA(kk + 2, a0); }
      { bf8 bf = cvt8_tril(bx1, by1, (kk + 1) * 32 + 8 * q, bdiag);
        domfma(a1, bf); loadB(kk + 5, bx1, by1); loadA(kk + 3, a1); }
      { bf8 bf = cvt8_tril(bx2, by2, (kk + 2) * 32 + 8 * q, bdiag);
        domfma(a0, bf); loadB(kk + 6, bx2, by2); loadA(kk + 4, a0); }
      { bf8 bf = cvt8_tril(bx3, by3, (kk + 3) * 32 + 8 * q, bdiag);
        domfma(a1, bf); loadB(kk + 7, bx3, by3); loadA(kk + 5, a1); }
    }

    // diag-step prefetch (y strips): in flight across the 4 peeled steps
    float4 dax[4], day[4], dbx, dby;
    int dI = 0;
    if (!is_z) {
      const int nb = (c0 - DZ) >> 5;   // 32x32 Ly block index
      dI = (c0 - DZ) & 31;             // group's base row within block
      const float* pb = Ly + ((size_t)nb * 32 + dI + lcol) * 32 + 8 * q;
      dbx = *(const float4*)pb; dby = *(const float4*)(pb + 4);
      #pragma unroll
      for (int mi = 0; mi < 4; ++mi) {
        const float* pa =
            eps + (size_t)(64 * mh + 16 * mi + lcol) * DT + DZ + nb * 32 + 8 * q;
        dax[mi] = *(const float4*)pa; day[mi] = *(const float4*)(pa + 4);
      }
    }

    // peeled steps 12..15 (buffers hold exactly 12,13,14,15)
    { bf8 bf = cvt8_tril(bx0, by0, 12 * 32 + 8 * q, bdiag);
      domfma(a0, bf); loadA(14, a0); }
    { bf8 bf = cvt8_tril(bx1, by1, 13 * 32 + 8 * q, bdiag);
      domfma(a1, bf); loadA(15, a1); }
    { bf8 bf = cvt8_tril(bx2, by2, 14 * 32 + 8 * q, bdiag); domfma(a0, bf); }
    { bf8 bf = cvt8_tril(bx3, by3, 15 * 32 + 8 * q, bdiag); domfma(a1, bf); }

    // block-diag einsum step (y strips only)
    if (!is_z) {
      bf8 bf = cvt8_tril(dbx, dby, 8 * q, dI + lcol);
      #pragma unroll
      for (int mi = 0; mi < 4; ++mi) {
        bf8 af = cvt8(dax[mi], day[mi]);
        acc[mi] = __builtin_amdgcn_mfma_f32_16x16x32_bf16(af, bf, acc[mi], 0, 0, 0);
      }
    }

    const float mval = mv[colL];
    #pragma unroll
    for (int mi = 0; mi < 4; ++mi) {
      #pragma unroll
      for (int r = 0; r < 4; ++r) {
        out[(size_t)(64 * mh + 16 * mi + 4 * q + r) * DT + colL] = acc[mi][r] + mval;
      }
    }
  }
}

extern "C" void kernel_launch(void* const* d_in, const int* in_sizes, int n_in,
                              void* d_out, int out_size, void* d_ws, size_t ws_size,
                              hipStream_t stream) {
  const float* m   = (const float*)d_in[0];
  const float* Lz  = (const float*)d_in[1];
  const float* Ly  = (const float*)d_in[2];
  const float* Lyz = (const float*)d_in[3];
  const float* eps = (const float*)d_in[4];
  float* out = (float*)d_out;
  sv_kernel<<<dim3(256), dim3(512), 0, stream>>>(m, Lz, Ly, Lyz, eps, out);
}

// Round 5
// 55.119 us; speedup vs baseline: 2.7976x; 1.1483x over previous
//
#include <hip/hip_runtime.h>

#define DZ 512
#define DT 66048
#define NT 4128  // 16-col output tiles
#define SV_JITTER 1e-4f

typedef __attribute__((ext_vector_type(8))) short bf8;
typedef __attribute__((ext_vector_type(4))) float f4;

__device__ __forceinline__ short f2bf(float f) {
  unsigned u = __builtin_bit_cast(unsigned, f);
  return (short)((u + 0x7FFFu + ((u >> 16) & 1u)) >> 16);
}

__device__ __forceinline__ bf8 cvt8(float4 a, float4 b) {
  bf8 r = { f2bf(a.x), f2bf(a.y), f2bf(a.z), f2bf(a.w),
            f2bf(b.x), f2bf(b.y), f2bf(b.z), f2bf(b.w) };
  return r;
}

// tril/jitter cvt: element t has k-index kbase+t
__device__ __forceinline__ bf8 cvt8_tril(float4 x, float4 y, int kbase, int diag) {
  float v[8] = {x.x, x.y, x.z, x.w, y.x, y.y, y.z, y.w};
  bf8 r;
  #pragma unroll
  for (int t = 0; t < 8; ++t) {
    int k = kbase + t;
    float val = (k < diag) ? v[t] : ((k == diag) ? v[t] + SV_JITTER : 0.f);
    r[t] = f2bf(val);
  }
  return r;
}

// One 16-col tile, all 128 samples (8 M-frags). B read once chip-wide.
// acc layout per mfma_f32_16x16x32_bf16: col=lane&15, row=4*(lane>>4)+reg.
template <bool IS_Z>
__device__ __forceinline__ void process_tile(
    int col0, int lcol, int q, int lane, const short* __restrict__ Afrag,
    const float* __restrict__ mv, const float* __restrict__ Lz,
    const float* __restrict__ Ly, const float* __restrict__ Lyz,
    const float* __restrict__ eps, float* __restrict__ out) {
  const int colL = col0 + lcol;
  const float* bptr = IS_Z ? (Lz + (size_t)colL * DZ)
                           : (Lyz + (size_t)(colL - DZ) * DZ);
  const int bdiag = colL;  // tril diag (IS_Z only)

  f4 acc[8];
  #pragma unroll
  for (int mi = 0; mi < 8; ++mi) acc[mi] = f4{0.f, 0.f, 0.f, 0.f};

  float4 bx0, by0, bx1, by1, bx2, by2, bx3, by3;
  bf8 a0[8], a1[8];

  auto loadB = [&](int kk, float4& x, float4& y) {
    const float* p = bptr + kk * 32 + 8 * q;
    x = *(const float4*)p;
    y = *(const float4*)(p + 4);
  };
  auto loadA = [&](int kk, bf8* a) {
    #pragma unroll
    for (int mi = 0; mi < 8; ++mi)
      a[mi] = *(const bf8*)&Afrag[(kk * 8 + mi) * 512 + lane * 8];
  };
  auto mk = [&](float4 x, float4 y, int kb) {
    return IS_Z ? cvt8_tril(x, y, kb, bdiag) : cvt8(x, y);
  };
  auto domfma = [&](const bf8* a, bf8 bf) {
    #pragma unroll
    for (int mi = 0; mi < 8; ++mi)
      acc[mi] = __builtin_amdgcn_mfma_f32_16x16x32_bf16(a[mi], bf, acc[mi], 0, 0, 0);
  };

  // prologue: B 4-deep, A 2-deep
  loadB(0, bx0, by0); loadB(1, bx1, by1);
  loadB(2, bx2, by2); loadB(3, bx3, by3);
  loadA(0, a0); loadA(1, a1);

  int kk = 0;
  #pragma unroll 1
  for (int kt = 0; kt < 3; ++kt, kk += 4) {  // steps 0..11, refills all < 16
    { bf8 bf = mk(bx0, by0, kk * 32 + 8 * q);
      domfma(a0, bf); loadB(kk + 4, bx0, by0); loadA(kk + 2, a0); }
    { bf8 bf = mk(bx1, by1, (kk + 1) * 32 + 8 * q);
      domfma(a1, bf); loadB(kk + 5, bx1, by1); loadA(kk + 3, a1); }
    { bf8 bf = mk(bx2, by2, (kk + 2) * 32 + 8 * q);
      domfma(a0, bf); loadB(kk + 6, bx2, by2); loadA(kk + 4, a0); }
    { bf8 bf = mk(bx3, by3, (kk + 3) * 32 + 8 * q);
      domfma(a1, bf); loadB(kk + 7, bx3, by3); loadA(kk + 5, a1); }
  }

  // diag-step B prefetch (y tiles): 8 regs, in flight across peeled steps
  float4 dbx{}, dby{};
  int nb = 0, dI = 0;
  if (!IS_Z) {
    nb = (col0 - DZ) >> 5;            // 32x32 Ly block
    dI = (col0 - DZ) & 31;            // tile's base row within block (0 or 16)
    const float* pb = Ly + ((size_t)nb * 32 + dI + lcol) * 32 + 8 * q;
    dbx = *(const float4*)pb; dby = *(const float4*)(pb + 4);
  }

  // peeled steps 12..15 (buffers hold exactly 12,13,14,15)
  { bf8 bf = mk(bx0, by0, 12 * 32 + 8 * q); domfma(a0, bf); loadA(14, a0); }
  { bf8 bf = mk(bx1, by1, 13 * 32 + 8 * q); domfma(a1, bf); loadA(15, a1); }
  { bf8 bf = mk(bx2, by2, 14 * 32 + 8 * q); domfma(a0, bf); }
  { bf8 bf = mk(bx3, by3, 15 * 32 + 8 * q); domfma(a1, bf); }

  // block-diag einsum step (y tiles): A from global (eps_y cols not staged)
  if (!IS_Z) {
    const bf8 dbf = cvt8_tril(dbx, dby, 8 * q, dI + lcol);
    const float* abase = eps + (size_t)lcol * DT + DZ + nb * 32 + 8 * q;
    float4 rx[4], ry[4];
    #pragma unroll
    for (int mi = 0; mi < 4; ++mi) {  // batch 1: rows 0..63
      const float* pa = abase + (size_t)mi * 16 * DT;
      rx[mi] = *(const float4*)pa; ry[mi] = *(const float4*)(pa + 4);
    }
    float4 sx[4], sy[4];
    #pragma unroll
    for (int mi = 0; mi < 4; ++mi) {  // batch 2: rows 64..127
      const float* pa = abase + (size_t)(mi + 4) * 16 * DT;
      sx[mi] = *(const float4*)pa; sy[mi] = *(const float4*)(pa + 4);
    }
    #pragma unroll
    for (int mi = 0; mi < 4; ++mi) {
      bf8 af = cvt8(rx[mi], ry[mi]);
      acc[mi] = __builtin_amdgcn_mfma_f32_16x16x32_bf16(af, dbf, acc[mi], 0, 0, 0);
    }
    #pragma unroll
    for (int mi = 0; mi < 4; ++mi) {
      bf8 af = cvt8(sx[mi], sy[mi]);
      acc[mi + 4] = __builtin_amdgcn_mfma_f32_16x16x32_bf16(af, dbf, acc[mi + 4], 0, 0, 0);
    }
  }

  const float mval = mv[colL];
  #pragma unroll
  for (int mi = 0; mi < 8; ++mi) {
    #pragma unroll
    for (int r = 0; r < 4; ++r) {
      out[(size_t)(16 * mi + 4 * q + r) * DT + colL] = acc[mi][r] + mval;
    }
  }
}

// 256 blocks (1/CU) x 512 threads (8 waves). Stage ALL of eps_z into LDS in
// MFMA-frag layout once; then each wave independently processes ~2 16-col
// tiles (T = r*2048 + b*8 + wv) with zero barriers.
__global__ __launch_bounds__(512, 2)
void sv_kernel(const float* __restrict__ mv, const float* __restrict__ Lz,
               const float* __restrict__ Ly, const float* __restrict__ Lyz,
               const float* __restrict__ eps, float* __restrict__ out) {
  // region r = kk*8+mi: slot==lane holds eps[16*mi+(lane&15)][kk*32+(lane>>4)*8..+7]
  __shared__ short Afrag[128 * 512];  // 128 KB

  const int tid = threadIdx.x;
  const int lane = tid & 63;
  const int wv = tid >> 6;
  const int lcol = lane & 15;
  const int q = lane >> 4;

  {  // stage eps_z once: wave-uniform region, slot=lane -> linear ds_write
    const int slot = tid & 63;
    const int r0 = (tid >> 6) * 16;
    #pragma unroll 4
    for (int i = 0; i < 16; ++i) {
      const int r = r0 + i;  // 0..127; mi=r&7, kk=r>>3
      const float* p = eps + (size_t)(16 * (r & 7) + (slot & 15)) * DT +
                       (r >> 3) * 32 + (slot >> 4) * 8;
      float4 x = *(const float4*)p;
      float4 y = *(const float4*)(p + 4);
      *(bf8*)&Afrag[r * 512 + slot * 8] = cvt8(x, y);
    }
  }
  __syncthreads();  // the ONLY barrier

  #pragma unroll 1
  for (int r = 0; r < 3; ++r) {
    const int T = r * 2048 + blockIdx.x * 8 + wv;
    if (T >= NT) break;
    const int col0 = T * 16;
    if (col0 < DZ)
      process_tile<true>(col0, lcol, q, lane, Afrag, mv, Lz, Ly, Lyz, eps, out);
    else
      process_tile<false>(col0, lcol, q, lane, Afrag, mv, Lz, Ly, Lyz, eps, out);
  }
}

extern "C" void kernel_launch(void* const* d_in, const int* in_sizes, int n_in,
                              void* d_out, int out_size, void* d_ws, size_t ws_size,
                              hipStream_t stream) {
  const float* m   = (const float*)d_in[0];
  const float* Lz  = (const float*)d_in[1];
  const float* Ly  = (const float*)d_in[2];
  const float* Lyz = (const float*)d_in[3];
  const float* eps = (const float*)d_in[4];
  float* out = (float*)d_out;
  sv_kernel<<<dim3(256), dim3(512), 0, stream>>>(m, Lz, Ly, Lyz, eps, out);
}

// Round 6
// 51.278 us; speedup vs baseline: 3.0072x; 1.0749x over previous
//
#include <hip/hip_runtime.h>

#define DZ 512
#define DT 66048
#define NT 4128  // 16-col output tiles
#define SV_JITTER 1e-4f

typedef __attribute__((ext_vector_type(8))) short bf8;
typedef __attribute__((ext_vector_type(4))) float f4;

__device__ __forceinline__ short f2bf(float f) {
  unsigned u = __builtin_bit_cast(unsigned, f);
  return (short)((u + 0x7FFFu + ((u >> 16) & 1u)) >> 16);
}

__device__ __forceinline__ bf8 cvt8(float4 a, float4 b) {
  bf8 r = { f2bf(a.x), f2bf(a.y), f2bf(a.z), f2bf(a.w),
            f2bf(b.x), f2bf(b.y), f2bf(b.z), f2bf(b.w) };
  return r;
}

// tril/jitter cvt: element t has k-index kbase+t
__device__ __forceinline__ bf8 cvt8_tril(float4 x, float4 y, int kbase, int diag) {
  float v[8] = {x.x, x.y, x.z, x.w, y.x, y.y, y.z, y.w};
  bf8 r;
  #pragma unroll
  for (int t = 0; t < 8; ++t) {
    int k = kbase + t;
    float val = (k < diag) ? v[t] : ((k == diag) ? v[t] + SV_JITTER : 0.f);
    r[t] = f2bf(val);
  }
  return r;
}

// One 16-col tile, all 128 samples (8 M-frags). B read once chip-wide.
// acc layout per mfma_f32_16x16x32_bf16: col=lane&15, row=4*(lane>>4)+reg.
template <bool IS_Z>
__device__ __forceinline__ void process_tile(
    int col0, int lcol, int q, int lane, const short* __restrict__ Afrag,
    const float* __restrict__ mv, const float* __restrict__ Lz,
    const float* __restrict__ Ly, const float* __restrict__ Lyz,
    const float* __restrict__ eps, float* __restrict__ out) {
  const int colL = col0 + lcol;
  const float* bptr = IS_Z ? (Lz + (size_t)colL * DZ)
                           : (Lyz + (size_t)(colL - DZ) * DZ);
  const int bdiag = colL;  // tril diag (IS_Z only)

  f4 acc[8];
  #pragma unroll
  for (int mi = 0; mi < 8; ++mi) acc[mi] = f4{0.f, 0.f, 0.f, 0.f};

  float4 bx0, by0, bx1, by1, bx2, by2, bx3, by3;
  bf8 a[8];  // single A buffer (keeps VGPR under the 4-wave/SIMD cap)

  auto loadB = [&](int kk, float4& x, float4& y) {
    const float* p = bptr + kk * 32 + 8 * q;
    x = *(const float4*)p;
    y = *(const float4*)(p + 4);
  };
  auto loadA = [&](int kk) {
    #pragma unroll
    for (int mi = 0; mi < 8; ++mi)
      a[mi] = *(const bf8*)&Afrag[(kk * 8 + mi) * 512 + lane * 8];
  };
  auto mk = [&](float4 x, float4 y, int kb) {
    return IS_Z ? cvt8_tril(x, y, kb, bdiag) : cvt8(x, y);
  };
  auto domfma = [&](bf8 bf) {
    #pragma unroll
    for (int mi = 0; mi < 8; ++mi)
      acc[mi] = __builtin_amdgcn_mfma_f32_16x16x32_bf16(a[mi], bf, acc[mi], 0, 0, 0);
  };

  // prologue: B 4-deep in flight
  loadB(0, bx0, by0); loadB(1, bx1, by1);
  loadB(2, bx2, by2); loadB(3, bx3, by3);

  int kk = 0;
  #pragma unroll 1
  for (int kt = 0; kt < 3; ++kt, kk += 4) {  // steps 0..11; refills all < 16
    { loadA(kk);
      bf8 bf = mk(bx0, by0, kk * 32 + 8 * q);
      loadB(kk + 4, bx0, by0); domfma(bf); }
    { loadA(kk + 1);
      bf8 bf = mk(bx1, by1, (kk + 1) * 32 + 8 * q);
      loadB(kk + 5, bx1, by1); domfma(bf); }
    { loadA(kk + 2);
      bf8 bf = mk(bx2, by2, (kk + 2) * 32 + 8 * q);
      loadB(kk + 6, bx2, by2); domfma(bf); }
    { loadA(kk + 3);
      bf8 bf = mk(bx3, by3, (kk + 3) * 32 + 8 * q);
      loadB(kk + 7, bx3, by3); domfma(bf); }
  }

  // diag-step B prefetch (y tiles): in flight across the peeled steps
  float4 dbx{}, dby{};
  int nb = 0, dI = 0;
  if (!IS_Z) {
    nb = (col0 - DZ) >> 5;            // 32x32 Ly block
    dI = (col0 - DZ) & 31;            // tile's base row within block (0 or 16)
    const float* pb = Ly + ((size_t)nb * 32 + dI + lcol) * 32 + 8 * q;
    dbx = *(const float4*)pb; dby = *(const float4*)(pb + 4);
  }

  // peeled steps 12..15 (buffers hold exactly 12,13,14,15)
  { loadA(12); bf8 bf = mk(bx0, by0, 12 * 32 + 8 * q); domfma(bf); }
  { loadA(13); bf8 bf = mk(bx1, by1, 13 * 32 + 8 * q); domfma(bf); }
  { loadA(14); bf8 bf = mk(bx2, by2, 14 * 32 + 8 * q); domfma(bf); }
  { loadA(15); bf8 bf = mk(bx3, by3, 15 * 32 + 8 * q); domfma(bf); }

  // block-diag einsum step (y tiles): A from global (eps_y cols not staged)
  if (!IS_Z) {
    const bf8 dbf = cvt8_tril(dbx, dby, 8 * q, dI + lcol);
    const float* abase = eps + (size_t)lcol * DT + DZ + nb * 32 + 8 * q;
    float4 rx[4], ry[4];
    #pragma unroll
    for (int mi = 0; mi < 4; ++mi) {  // batch 1: rows 0..63
      const float* pa = abase + (size_t)mi * 16 * DT;
      rx[mi] = *(const float4*)pa; ry[mi] = *(const float4*)(pa + 4);
    }
    #pragma unroll
    for (int mi = 0; mi < 4; ++mi) {
      bf8 af = cvt8(rx[mi], ry[mi]);
      acc[mi] = __builtin_amdgcn_mfma_f32_16x16x32_bf16(af, dbf, acc[mi], 0, 0, 0);
    }
    #pragma unroll
    for (int mi = 0; mi < 4; ++mi) {  // batch 2: rows 64..127
      const float* pa = abase + (size_t)(mi + 4) * 16 * DT;
      rx[mi] = *(const float4*)pa; ry[mi] = *(const float4*)(pa + 4);
    }
    #pragma unroll
    for (int mi = 0; mi < 4; ++mi) {
      bf8 af = cvt8(rx[mi], ry[mi]);
      acc[mi + 4] = __builtin_amdgcn_mfma_f32_16x16x32_bf16(af, dbf, acc[mi + 4], 0, 0, 0);
    }
  }

  const float mval = mv[colL];
  #pragma unroll
  for (int mi = 0; mi < 8; ++mi) {
    #pragma unroll
    for (int r = 0; r < 4; ++r) {
      out[(size_t)(16 * mi + 4 * q + r) * DT + colL] = acc[mi][r] + mval;
    }
  }
}

// 256 blocks (1/CU) x 1024 threads (16 waves = 4/SIMD). Stage ALL of eps_z
// into LDS in MFMA-frag layout once; then each wave independently processes
// ONE 16-col tile (T = b*16 + wv), zero barriers after staging. Wave 15 of
// blocks 0..31 takes one extra tile (4096+b).
__global__ __launch_bounds__(1024, 4)
void sv_kernel(const float* __restrict__ mv, const float* __restrict__ Lz,
               const float* __restrict__ Ly, const float* __restrict__ Lyz,
               const float* __restrict__ eps, float* __restrict__ out) {
  // region r = kk*8+mi: slot==lane holds eps[16*mi+(lane&15)][kk*32+(lane>>4)*8..+7]
  __shared__ short Afrag[128 * 512];  // 128 KB

  const int tid = threadIdx.x;
  const int lane = tid & 63;
  const int wv = tid >> 6;
  const int lcol = lane & 15;
  const int q = lane >> 4;

  {  // stage eps_z once: wave-uniform region, slot=lane -> linear ds_write
    const int slot = lane;
    const int r0 = wv * 8;
    #pragma unroll 4
    for (int i = 0; i < 8; ++i) {
      const int r = r0 + i;  // 0..127; mi=r&7, kk=r>>3
      const float* p = eps + (size_t)(16 * (r & 7) + (slot & 15)) * DT +
                       (r >> 3) * 32 + (slot >> 4) * 8;
      float4 x = *(const float4*)p;
      float4 y = *(const float4*)(p + 4);
      *(bf8*)&Afrag[r * 512 + slot * 8] = cvt8(x, y);
    }
  }
  __syncthreads();  // the ONLY barrier

  {
    const int T = blockIdx.x * 16 + wv;  // 0..4095
    const int col0 = T * 16;
    if (col0 < DZ)
      process_tile<true>(col0, lcol, q, lane, Afrag, mv, Lz, Ly, Lyz, eps, out);
    else
      process_tile<false>(col0, lcol, q, lane, Afrag, mv, Lz, Ly, Lyz, eps, out);
  }
  if (wv == 15 && blockIdx.x < 32) {  // leftover tiles 4096..4127 (all y)
    const int col0 = (4096 + blockIdx.x) * 16;
    process_tile<false>(col0, lcol, q, lane, Afrag, mv, Lz, Ly, Lyz, eps, out);
  }
}

extern "C" void kernel_launch(void* const* d_in, const int* in_sizes, int n_in,
                              void* d_out, int out_size, void* d_ws, size_t ws_size,
                              hipStream_t stream) {
  const float* m   = (const float*)d_in[0];
  const float* Lz  = (const float*)d_in[1];
  const float* Ly  = (const float*)d_in[2];
  const float* Lyz = (const float*)d_in[3];
  const float* eps = (const float*)d_in[4];
  float* out = (float*)d_out;
  sv_kernel<<<dim3(256), dim3(1024), 0, stream>>>(m, Lz, Ly, Lyz, eps, out);
}